// Round 6
// baseline (80.222 us; speedup 1.0000x reference)
//
#include <hip/hip_runtime.h>
#include <math.h>

#define B_ 2
#define SQ_ 1024
#define SK_ 1024
#define D_ 64
#define DV_ 64
#define QB 4
#define KSPLIT 4
#define KTILE 256            // keys per block
#define CE 60.0f             // p = exp(CE - dist); shared bias, no max pass
#define QSCALE 2048.0f
#define QINV (1.0f / 2048.0f)

// d_ws layout (u32 units):
//   wsq  [0,      65536)   q u16-packed pairs [B][SQ][32]
//   wsk  [65536, 131072)   k u16-packed pairs [B][SK][32]
//   wsv  [131072,196608)   v bf16-packed pairs [B][SK][32]
//   ws_o [196608,720896)   fp32 partial O [row=B*SQ][KSPLIT][64]
//   ws_l [720896,729088)   fp32 partial l [row][KSPLIT]

__device__ inline unsigned int pk2(float x, float y) {
  int xi = (int)rintf(fminf(fmaxf(x, -15.9f), 15.9f) * QSCALE) + 32768;
  int yi = (int)rintf(fminf(fmaxf(y, -15.9f), 15.9f) * QSCALE) + 32768;
  return (unsigned int)(xi & 0xffff) | ((unsigned int)yi << 16);
}

__device__ inline unsigned int bfp2(float lo, float hi) {  // bf16 RNE pair
  union { float f; unsigned int u; } a, b;
  a.f = lo; b.f = hi;
  unsigned int ua = a.u + 0x7fff + ((a.u >> 16) & 1);
  unsigned int ub = b.u + 0x7fff + ((b.u >> 16) & 1);
  return (ua >> 16) | (ub & 0xffff0000u);
}

// ---- Kernel 1: quantize q,k -> u16 ; v -> bf16 ----
__global__ __launch_bounds__(256) void convert_qkv(
    const float* __restrict__ qg, const float* __restrict__ kg,
    const float* __restrict__ vg, unsigned int* __restrict__ ws) {
  const int t = blockIdx.x * 256 + threadIdx.x;
  uint4 r;
  if (t < 32768) {
    const float4* s4 = (t < 16384) ? (const float4*)qg : (const float4*)kg;
    const int idx = t & 16383;
    float4 a = s4[idx * 2], b = s4[idx * 2 + 1];
    r.x = pk2(a.x, a.y); r.y = pk2(a.z, a.w);
    r.z = pk2(b.x, b.y); r.w = pk2(b.z, b.w);
  } else {
    const int idx = t - 32768;
    float4 a = ((const float4*)vg)[idx * 2], b = ((const float4*)vg)[idx * 2 + 1];
    r.x = bfp2(a.x, a.y); r.y = bfp2(a.z, a.w);
    r.z = bfp2(b.x, b.y); r.w = bfp2(b.z, b.w);
  }
  ((uint4*)ws)[t] = r;
}

// ---- Kernel 2: partial attention, chunked LDS pipeline ----
// grid = B * (SQ/QB) * KSPLIT = 2048 blocks x 256 threads.
// Per block: 4 queries x 256 keys. K (32KB u16) + V (32KB bf16) streamed as
// 4 x 16KB chunks through a 2-buffer LDS stage; 4 uint4 global loads/thread
// per chunk issued ahead of current-chunk compute.
__global__ __launch_bounds__(256, 4) void manh_main(
    const unsigned int* __restrict__ ws, const int* __restrict__ maskg,
    float* __restrict__ ws_o, float* __restrict__ ws_l) {
  __shared__ uint4 stage[2][1024];   // 2 x 16 KB
  __shared__ float4 p4s[KTILE];      // 4 KB probs, key-major [k][4q]
  __shared__ float4 redl[4];         // per-wave l partials

  const unsigned int* wsq = ws;
  const unsigned int* wsk = ws + 65536;
  const unsigned int* wsv = ws + 131072;

  const int tid = threadIdx.x;
  const int wid = tid >> 6;
  const int split = blockIdx.x & 3;
  const int qgrp = (blockIdx.x >> 2) & 255;
  const int b = blockIdx.x >> 10;
  const int q0 = qgrp * QB;
  const int kbase = split * KTILE;

  const int kq = tid >> 2;  // key within 64-key pass
  const int qt = tid & 3;   // dim quarter (16 dims = 2 uint4)

  // q fragments: this thread's dim-quarter of 4 query rows (32 VGPRs)
  const uint4* qrow4 = (const uint4*)(wsq + ((size_t)b * SQ_ + q0) * 32);
  uint4 qr[QB][2];
#pragma unroll
  for (int q = 0; q < QB; ++q) {
    qr[q][0] = qrow4[q * 8 + qt * 2];
    qr[q][1] = qrow4[q * 8 + qt * 2 + 1];
  }

  // chunk sources (uint4 granularity): K chunks 0,1 then V chunks 0,1
  const uint4* ksrc = (const uint4*)(wsk + (size_t)b * SK_ * 32) + kbase * 8;
  const uint4* vsrc = (const uint4*)(wsv + (size_t)b * SK_ * 32) + kbase * 8;
  const int* mb = maskg + (size_t)b * SK_ + kbase;

  uint4 r0, r1, r2, r3;
#define LOADC(src, c)                                   \
  r0 = (src)[(c) * 1024 + tid];                         \
  r1 = (src)[(c) * 1024 + tid + 256];                   \
  r2 = (src)[(c) * 1024 + tid + 512];                   \
  r3 = (src)[(c) * 1024 + tid + 768];
#define WRITEC(buf)                                     \
  stage[buf][tid] = r0;                                 \
  stage[buf][tid + 256] = r1;                           \
  stage[buf][tid + 512] = r2;                           \
  stage[buf][tid + 768] = r3;

  float lsum[QB] = {0.f, 0.f, 0.f, 0.f};

  // sad over one 64-key pass from LDS buf; pass p keys [64p..64p+63] of tile
  auto sad_pass = [&](int buf, int p) {
    const int kl = (p & 1) * 64 + kq;  // key within the 128-key chunk
    const uint4* kb = &stage[buf][0];
    uint4 kc0 = kb[kl * 8 + qt * 2];
    uint4 kc1 = kb[kl * 8 + qt * 2 + 1];
    unsigned int d[QB] = {0u, 0u, 0u, 0u};
#pragma unroll
    for (int q = 0; q < QB; ++q) {
      d[q] = __builtin_amdgcn_sad_u16(qr[q][0].x, kc0.x, d[q]);
      d[q] = __builtin_amdgcn_sad_u16(qr[q][0].y, kc0.y, d[q]);
      d[q] = __builtin_amdgcn_sad_u16(qr[q][0].z, kc0.z, d[q]);
      d[q] = __builtin_amdgcn_sad_u16(qr[q][0].w, kc0.w, d[q]);
      d[q] = __builtin_amdgcn_sad_u16(qr[q][1].x, kc1.x, d[q]);
      d[q] = __builtin_amdgcn_sad_u16(qr[q][1].y, kc1.y, d[q]);
      d[q] = __builtin_amdgcn_sad_u16(qr[q][1].z, kc1.z, d[q]);
      d[q] = __builtin_amdgcn_sad_u16(qr[q][1].w, kc1.w, d[q]);
    }
#pragma unroll
    for (int q = 0; q < QB; ++q) {
      d[q] += __shfl_xor(d[q], 1, 64);
      d[q] += __shfl_xor(d[q], 2, 64);
    }
    if ((tid & 3) == p) {  // owner lane: one (pass,key) per thread
      const int key = p * 64 + kq;
      const int mk = mb[key];
      float4 e;
      e.x = mk ? __expf(fmaf(-(float)d[0], QINV, CE)) : 0.f;
      e.y = mk ? __expf(fmaf(-(float)d[1], QINV, CE)) : 0.f;
      e.z = mk ? __expf(fmaf(-(float)d[2], QINV, CE)) : 0.f;
      e.w = mk ? __expf(fmaf(-(float)d[3], QINV, CE)) : 0.f;
      p4s[key] = e;
      lsum[0] += e.x; lsum[1] += e.y; lsum[2] += e.z; lsum[3] += e.w;
    }
  };

  const int col = tid & 15;          // 4 dv dims (uint2 of bf16 pairs)
  const int slot = (tid >> 4) & 15;  // 16 key slots
  float4 acc[QB];
#pragma unroll
  for (int q = 0; q < QB; ++q) acc[q] = make_float4(0.f, 0.f, 0.f, 0.f);

  // PV over one 128-key chunk from LDS buf (chunk vi of V: keys 128*vi..)
  auto pv_chunk = [&](int buf, int vi) {
#pragma unroll
    for (int t = 0; t < 8; ++t) {
      const int kl = slot + 16 * t;  // key within chunk
      uint2 vr = ((const uint2*)&stage[buf][0])[kl * 16 + col];
      float4 pw = p4s[vi * 128 + kl];
      union { unsigned int u; float f; } v0, v1, v2, v3;
      v0.u = vr.x << 16; v1.u = vr.x & 0xffff0000u;
      v2.u = vr.y << 16; v3.u = vr.y & 0xffff0000u;
      acc[0].x += pw.x * v0.f; acc[0].y += pw.x * v1.f;
      acc[0].z += pw.x * v2.f; acc[0].w += pw.x * v3.f;
      acc[1].x += pw.y * v0.f; acc[1].y += pw.y * v1.f;
      acc[1].z += pw.y * v2.f; acc[1].w += pw.y * v3.f;
      acc[2].x += pw.z * v0.f; acc[2].y += pw.z * v1.f;
      acc[2].z += pw.z * v2.f; acc[2].w += pw.z * v3.f;
      acc[3].x += pw.w * v0.f; acc[3].y += pw.w * v1.f;
      acc[3].z += pw.w * v2.f; acc[3].w += pw.w * v3.f;
    }
  };

  // ---- pipeline: K0, K1, V0, V1 through the 2-buffer stage ----
  LOADC(ksrc, 0); WRITEC(0); __syncthreads();
  LOADC(ksrc, 1);            // overlap with sad on K0
  sad_pass(0, 0); sad_pass(0, 1);
  WRITEC(1); __syncthreads();
  LOADC(vsrc, 0);            // overlap with sad on K1
  sad_pass(1, 2); sad_pass(1, 3);
  // l reduction (all sads done)
#pragma unroll
  for (int off = 32; off > 0; off >>= 1)
#pragma unroll
    for (int q = 0; q < QB; ++q) lsum[q] += __shfl_down(lsum[q], off, 64);
  if ((tid & 63) == 0)
    redl[wid] = make_float4(lsum[0], lsum[1], lsum[2], lsum[3]);
  WRITEC(0); __syncthreads();
  LOADC(vsrc, 1);            // overlap with PV on V0
  pv_chunk(0, 0);
  WRITEC(1); __syncthreads();
  pv_chunk(1, 1);

  // intra-wave slot combine (lane bits 4,5)
#pragma unroll
  for (int q = 0; q < QB; ++q) {
    acc[q].x += __shfl_xor(acc[q].x, 16, 64);
    acc[q].y += __shfl_xor(acc[q].y, 16, 64);
    acc[q].z += __shfl_xor(acc[q].z, 16, 64);
    acc[q].w += __shfl_xor(acc[q].w, 16, 64);
    acc[q].x += __shfl_xor(acc[q].x, 32, 64);
    acc[q].y += __shfl_xor(acc[q].y, 32, 64);
    acc[q].z += __shfl_xor(acc[q].z, 32, 64);
    acc[q].w += __shfl_xor(acc[q].w, 32, 64);
  }
  __syncthreads();  // all PV reads of stage done; reuse stage[0] for pv
  float* pvf = (float*)&stage[0][0];  // [wid][q][64]
  if ((tid & 63) < 16) {
#pragma unroll
    for (int q = 0; q < QB; ++q)
      ((float4*)&pvf[(wid * QB + q) * DV_])[col] = acc[q];
  }
  __syncthreads();

  // epilogue: 256 threads = 4 q x 64 dims; write split partials
  const int q2 = tid >> 6;
  const int d2 = tid & 63;
  float o = pvf[(0 * QB + q2) * DV_ + d2] + pvf[(1 * QB + q2) * DV_ + d2] +
            pvf[(2 * QB + q2) * DV_ + d2] + pvf[(3 * QB + q2) * DV_ + d2];
  const size_t row = (size_t)b * SQ_ + q0 + q2;
  ws_o[(row * KSPLIT + split) * DV_ + d2] = o;
  if (d2 == 0) {
    const float* rl = (const float*)redl;
    float l = rl[0 * 4 + q2] + rl[1 * 4 + q2] + rl[2 * 4 + q2] + rl[3 * 4 + q2];
    ws_l[row * KSPLIT + split] = l;
  }
#undef LOADC
#undef WRITEC
}

// ---- Kernel 3: combine 4 splits (shared bias -> partials just add) ----
__global__ __launch_bounds__(256) void manh_combine(
    const float* __restrict__ ws_o, const float* __restrict__ ws_l,
    float* __restrict__ outg) {
  const int gid = blockIdx.x * 256 + threadIdx.x;
  const int r = gid >> 6;
  const int d = gid & 63;
  const float l = ws_l[r * 4] + ws_l[r * 4 + 1] + ws_l[r * 4 + 2] +
                  ws_l[r * 4 + 3];
  const float o = ws_o[(r * 4 + 0) * DV_ + d] + ws_o[(r * 4 + 1) * DV_ + d] +
                  ws_o[(r * 4 + 2) * DV_ + d] + ws_o[(r * 4 + 3) * DV_ + d];
  outg[(size_t)r * DV_ + d] = o / l;
}

extern "C" void kernel_launch(void* const* d_in, const int* in_sizes, int n_in,
                              void* d_out, int out_size, void* d_ws,
                              size_t ws_size, hipStream_t stream) {
  const float* q = (const float*)d_in[0];
  const float* k = (const float*)d_in[1];
  const float* v = (const float*)d_in[2];
  const int* mask = (const int*)d_in[3];
  float* out = (float*)d_out;

  unsigned int* ws = (unsigned int*)d_ws;
  float* ws_o = (float*)(ws + 196608);
  float* ws_l = (float*)(ws + 720896);

  convert_qkv<<<dim3(192), dim3(256), 0, stream>>>(q, k, v, ws);
  manh_main<<<dim3(B_ * (SQ_ / QB) * KSPLIT), dim3(256), 0, stream>>>(
      ws, mask, ws_o, ws_l);
  manh_combine<<<dim3(B_ * SQ_ * DV_ / 256), dim3(256), 0, stream>>>(
      ws_o, ws_l, out);
}

// Round 7
// 76.983 us; speedup vs baseline: 1.0421x; 1.0421x over previous
//
#include <hip/hip_runtime.h>
#include <math.h>

#define B_ 2
#define SQ_ 1024
#define SK_ 1024
#define D_ 64
#define DV_ 64
#define QB 4
#define KSPLIT 8
#define KTILE 128            // keys per block == threads per block
#define TPB 128
#define CE 60.0f             // p = exp(CE - dist); shared bias, no max pass
#define QSCALE 2048.0f
#define QINV (1.0f / 2048.0f)

// d_ws layout (u32 units):
//   wsq  [0,      65536)     q u16-packed pairs [B][SQ][32]
//   wsk  [65536, 131072)     k u16-packed pairs [B][SK][32]
//   wsv  [131072,196608)     v bf16-packed pairs [B][SK][32]
//   ws_o [196608, 1245184)   fp32 partial O [row=B*SQ][KSPLIT][64]
//   ws_l [1245184,1261568)   fp32 partial l [row][KSPLIT]

__device__ inline unsigned int pk2(float x, float y) {
  int xi = (int)rintf(fminf(fmaxf(x, -15.9f), 15.9f) * QSCALE) + 32768;
  int yi = (int)rintf(fminf(fmaxf(y, -15.9f), 15.9f) * QSCALE) + 32768;
  return (unsigned int)(xi & 0xffff) | ((unsigned int)yi << 16);
}

__device__ inline unsigned int bfp2(float lo, float hi) {  // bf16 RNE pair
  union { float f; unsigned int u; } a, b;
  a.f = lo; b.f = hi;
  unsigned int ua = a.u + 0x7fff + ((a.u >> 16) & 1);
  unsigned int ub = b.u + 0x7fff + ((b.u >> 16) & 1);
  return (ua >> 16) | (ub & 0xffff0000u);
}

// ---- Kernel 1: quantize q,k -> u16 ; v -> bf16 ----
__global__ __launch_bounds__(256) void convert_qkv(
    const float* __restrict__ qg, const float* __restrict__ kg,
    const float* __restrict__ vg, unsigned int* __restrict__ ws) {
  const int t = blockIdx.x * 256 + threadIdx.x;
  uint4 r;
  if (t < 32768) {
    const float4* s4 = (t < 16384) ? (const float4*)qg : (const float4*)kg;
    const int idx = t & 16383;
    float4 a = s4[idx * 2], b = s4[idx * 2 + 1];
    r.x = pk2(a.x, a.y); r.y = pk2(a.z, a.w);
    r.z = pk2(b.x, b.y); r.w = pk2(b.z, b.w);
  } else {
    const int idx = t - 32768;
    float4 a = ((const float4*)vg)[idx * 2], b = ((const float4*)vg)[idx * 2 + 1];
    r.x = bfp2(a.x, a.y); r.y = bfp2(a.z, a.w);
    r.z = bfp2(b.x, b.y); r.w = bfp2(b.z, b.w);
  }
  ((uint4*)ws)[t] = r;
}

// ---- Kernel 2: partial attention, 1 key per thread ----
// grid = B * (SQ/QB) * KSPLIT = 4096 blocks x 128 threads.
// Per block: 4 queries x 128 keys. Whole-key sad in-register (no shuffles),
// q rows from LDS (uniform broadcast), K/V streamed from global (L1/L2).
__global__ __launch_bounds__(TPB, 8) void manh_main(
    const unsigned int* __restrict__ ws, const int* __restrict__ maskg,
    float* __restrict__ ws_o, float* __restrict__ ws_l) {
  __shared__ uint4 qs[QB * 8];        // 512 B: 4 q rows, u16-packed
  __shared__ float4 p4s[KTILE];       // 2 KB probs, key-major [k][4q]
  __shared__ float pvf[4][QB][DV_];   // 4 KB PV group partials
  __shared__ float4 redl[2];          // per-wave l partials

  const unsigned int* wsq = ws;
  const unsigned int* wsk = ws + 65536;
  const unsigned int* wsv = ws + 131072;

  const int tid = threadIdx.x;
  const int split = blockIdx.x & 7;
  const int qgrp = (blockIdx.x >> 3) & 255;
  const int b = blockIdx.x >> 11;
  const int q0 = qgrp * QB;
  const int kbase = split * KTILE;

  if (tid < 32)
    qs[tid] = ((const uint4*)(wsq + ((size_t)b * SQ_ + q0) * 32))[tid];
  __syncthreads();

  // ---- Phase 1: whole-key L1 distance, this thread's key = kbase+tid ----
  const int key = kbase + tid;
  const uint4* kr = (const uint4*)(wsk + (size_t)b * SK_ * 32) + (size_t)key * 8;
  unsigned int d[QB] = {0u, 0u, 0u, 0u};
#pragma unroll 2
  for (int j = 0; j < 8; ++j) {
    const uint4 kc = kr[j];
#pragma unroll
    for (int q = 0; q < QB; ++q) {
      const uint4 qv = qs[q * 8 + j];  // wave-uniform LDS broadcast
      d[q] = __builtin_amdgcn_sad_u16(qv.x, kc.x, d[q]);
      d[q] = __builtin_amdgcn_sad_u16(qv.y, kc.y, d[q]);
      d[q] = __builtin_amdgcn_sad_u16(qv.z, kc.z, d[q]);
      d[q] = __builtin_amdgcn_sad_u16(qv.w, kc.w, d[q]);
    }
  }
  const int mk = maskg[(size_t)b * SK_ + key];
  float4 e;
  e.x = mk ? __expf(fmaf(-(float)d[0], QINV, CE)) : 0.f;
  e.y = mk ? __expf(fmaf(-(float)d[1], QINV, CE)) : 0.f;
  e.z = mk ? __expf(fmaf(-(float)d[2], QINV, CE)) : 0.f;
  e.w = mk ? __expf(fmaf(-(float)d[3], QINV, CE)) : 0.f;
  p4s[tid] = e;

  float lsum[QB] = {e.x, e.y, e.z, e.w};
#pragma unroll
  for (int off = 32; off > 0; off >>= 1)
#pragma unroll
    for (int q = 0; q < QB; ++q) lsum[q] += __shfl_down(lsum[q], off, 64);
  if ((tid & 63) == 0)
    redl[tid >> 6] = make_float4(lsum[0], lsum[1], lsum[2], lsum[3]);
  __syncthreads();  // p4s + redl visible

  // ---- Phase 2: PV. 4 key-groups x 32 dim-pairs; 32 keys/thread ----
  const int kg = tid >> 5;  // key group (32 keys)
  const int c = tid & 31;   // bf16 dim pair -> dims 2c, 2c+1
  const unsigned int* vb = wsv + (size_t)b * SK_ * 32 +
                           (size_t)(kbase + kg * 32) * 32 + c;
  float a0x = 0.f, a0y = 0.f, a1x = 0.f, a1y = 0.f;
  float a2x = 0.f, a2y = 0.f, a3x = 0.f, a3y = 0.f;
#pragma unroll 4
  for (int t = 0; t < 32; ++t) {
    const unsigned int vr = vb[(size_t)t * 32];  // coalesced 128B/half-wave
    const float4 pw = p4s[kg * 32 + t];          // 2-addr broadcast (free)
    union { unsigned int u; float f; } v0, v1;
    v0.u = vr << 16; v1.u = vr & 0xffff0000u;
    a0x += pw.x * v0.f; a0y += pw.x * v1.f;
    a1x += pw.y * v0.f; a1y += pw.y * v1.f;
    a2x += pw.z * v0.f; a2y += pw.z * v1.f;
    a3x += pw.w * v0.f; a3y += pw.w * v1.f;
  }
  *(float2*)&pvf[kg][0][c * 2] = make_float2(a0x, a0y);
  *(float2*)&pvf[kg][1][c * 2] = make_float2(a1x, a1y);
  *(float2*)&pvf[kg][2][c * 2] = make_float2(a2x, a2y);
  *(float2*)&pvf[kg][3][c * 2] = make_float2(a3x, a3y);
  __syncthreads();

  // ---- epilogue: 256 outputs (4q x 64d) over 128 threads ----
#pragma unroll
  for (int r = 0; r < 2; ++r) {
    const int idx = tid + r * TPB;
    const int q2 = idx >> 6;
    const int d2 = idx & 63;
    const float o = pvf[0][q2][d2] + pvf[1][q2][d2] + pvf[2][q2][d2] +
                    pvf[3][q2][d2];
    const size_t row = (size_t)b * SQ_ + q0 + q2;
    ws_o[(row * KSPLIT + split) * DV_ + d2] = o;
    if (d2 == 0) {
      const float* rl = (const float*)redl;
      ws_l[row * KSPLIT + split] = rl[q2] + rl[4 + q2];
    }
  }
}

// ---- Kernel 3: combine 8 splits (shared bias -> partials just add) ----
__global__ __launch_bounds__(256) void manh_combine(
    const float* __restrict__ ws_o, const float* __restrict__ ws_l,
    float* __restrict__ outg) {
  const int gid = blockIdx.x * 256 + threadIdx.x;
  const int r = gid >> 6;
  const int d = gid & 63;
  float l = 0.f, o = 0.f;
#pragma unroll
  for (int s = 0; s < KSPLIT; ++s) {
    l += ws_l[r * KSPLIT + s];
    o += ws_o[(r * KSPLIT + s) * DV_ + d];
  }
  outg[(size_t)r * DV_ + d] = o / l;
}

extern "C" void kernel_launch(void* const* d_in, const int* in_sizes, int n_in,
                              void* d_out, int out_size, void* d_ws,
                              size_t ws_size, hipStream_t stream) {
  const float* q = (const float*)d_in[0];
  const float* k = (const float*)d_in[1];
  const float* v = (const float*)d_in[2];
  const int* mask = (const int*)d_in[3];
  float* out = (float*)d_out;

  unsigned int* ws = (unsigned int*)d_ws;
  float* ws_o = (float*)(ws + 196608);
  float* ws_l = (float*)(ws + 1245184);

  convert_qkv<<<dim3(192), dim3(256), 0, stream>>>(q, k, v, ws);
  manh_main<<<dim3(B_ * (SQ_ / QB) * KSPLIT), dim3(TPB), 0, stream>>>(
      ws, mask, ws_o, ws_l);
  manh_combine<<<dim3(B_ * SQ_ * DV_ / 256), dim3(256), 0, stream>>>(
      ws_o, ws_l, out);
}